// Round 1
// baseline (35.992 us; speedup 1.0000x reference)
//
#include <hip/hip_runtime.h>
#include <math.h>

// Spe loss: per-pixel cosine-angle between x[:, :, h, w] and y[:, :, h, w]
// reduced over B*C=1024, then mean of acos over 144*144 pixels.
// Memory-bound: 170 MB read once.

constexpr int PLANE = 144 * 144;     // 20736 pixels per (b,c) plane (contiguous)
constexpr int QUADS = PLANE / 4;     // 5184 float4 quads per plane
constexpr int BC    = 16 * 64;       // 1024 reduction depth
constexpr int QPB   = 16;            // pixel-quads per block (64 pixels)
constexpr int NG    = 32;            // bc groups per block
constexpr int NBLK  = QUADS / QPB;   // 324 blocks

__device__ inline void xor_fold(float4& v, int mask) {
    v.x += __shfl_xor(v.x, mask);
    v.y += __shfl_xor(v.y, mask);
    v.z += __shfl_xor(v.z, mask);
    v.w += __shfl_xor(v.w, mask);
}

__global__ __launch_bounds__(512) void spe_partial(const float4* __restrict__ x,
                                                   const float4* __restrict__ y,
                                                   float* __restrict__ bsum)
{
    const int tid = threadIdx.x;
    const int q   = tid & (QPB - 1);   // quad within block: 0..15
    const int g   = tid >> 4;          // bc group: 0..31
    const int qg  = blockIdx.x * QPB + q;

    float4 fz = make_float4(0.f, 0.f, 0.f, 0.f);
    float4 xx = make_float4(0.f, 0.f, 0.f, 0.f);
    float4 yy = make_float4(0.f, 0.f, 0.f, 0.f);

    size_t idx = (size_t)g * QUADS + (size_t)qg;
    const size_t step = (size_t)NG * QUADS;
    #pragma unroll 4
    for (int i = 0; i < BC / NG; ++i) {       // 32 iterations
        float4 a = x[idx];
        float4 b = y[idx];
        fz.x = fmaf(a.x, b.x, fz.x); fz.y = fmaf(a.y, b.y, fz.y);
        fz.z = fmaf(a.z, b.z, fz.z); fz.w = fmaf(a.w, b.w, fz.w);
        xx.x = fmaf(a.x, a.x, xx.x); xx.y = fmaf(a.y, a.y, xx.y);
        xx.z = fmaf(a.z, a.z, xx.z); xx.w = fmaf(a.w, a.w, xx.w);
        yy.x = fmaf(b.x, b.x, yy.x); yy.y = fmaf(b.y, b.y, yy.y);
        yy.z = fmaf(b.z, b.z, yy.z); yy.w = fmaf(b.w, b.w, yy.w);
        idx += step;
    }

    // Fold the wave's 4 bc-groups (tid bits 4,5) in-register.
    xor_fold(fz, 16); xor_fold(fz, 32);
    xor_fold(xx, 16); xor_fold(xx, 32);
    xor_fold(yy, 16); xor_fold(yy, 32);

    // Cross-wave fold via LDS: 8 waves x 16 quads.
    __shared__ float4 lfz[8][QPB], lxx[8][QPB], lyy[8][QPB];
    const int wave = tid >> 6;
    if ((tid & 63) < QPB) {
        lfz[wave][q] = fz; lxx[wave][q] = xx; lyy[wave][q] = yy;
    }
    __syncthreads();

    float s = 0.f;
    if (tid < QPB) {
        float4 F = lfz[0][tid], X = lxx[0][tid], Y = lyy[0][tid];
        #pragma unroll
        for (int wv = 1; wv < 8; ++wv) {
            F.x += lfz[wv][tid].x; F.y += lfz[wv][tid].y;
            F.z += lfz[wv][tid].z; F.w += lfz[wv][tid].w;
            X.x += lxx[wv][tid].x; X.y += lxx[wv][tid].y;
            X.z += lxx[wv][tid].z; X.w += lxx[wv][tid].w;
            Y.x += lyy[wv][tid].x; Y.y += lyy[wv][tid].y;
            Y.z += lyy[wv][tid].z; Y.w += lyy[wv][tid].w;
        }
        float r0 = F.x / (sqrtf(X.x) * sqrtf(Y.x));
        float r1 = F.y / (sqrtf(X.y) * sqrtf(Y.y));
        float r2 = F.z / (sqrtf(X.z) * sqrtf(Y.z));
        float r3 = F.w / (sqrtf(X.w) * sqrtf(Y.w));
        r0 = fminf(1.f, fmaxf(-1.f, r0));
        r1 = fminf(1.f, fmaxf(-1.f, r1));
        r2 = fminf(1.f, fmaxf(-1.f, r2));
        r3 = fminf(1.f, fmaxf(-1.f, r3));
        s = acosf(r0) + acosf(r1) + acosf(r2) + acosf(r3);
    }
    // Wave-0 tree reduction of the 16 quad sums (lanes 16..63 hold 0).
    if (tid < 64) {
        #pragma unroll
        for (int off = 32; off >= 1; off >>= 1) s += __shfl_down(s, off);
        if (tid == 0) bsum[blockIdx.x] = s;
    }
}

__global__ __launch_bounds__(512) void spe_final(const float* __restrict__ bsum,
                                                 float* __restrict__ out)
{
    __shared__ float l[8];
    const int t = threadIdx.x;
    float s = (t < NBLK) ? bsum[t] : 0.f;
    #pragma unroll
    for (int off = 32; off >= 1; off >>= 1) s += __shfl_down(s, off);
    if ((t & 63) == 0) l[t >> 6] = s;
    __syncthreads();
    if (t == 0) {
        float tot = 0.f;
        #pragma unroll
        for (int i = 0; i < 8; ++i) tot += l[i];
        out[0] = tot * (1.0f / (float)PLANE);
    }
}

extern "C" void kernel_launch(void* const* d_in, const int* in_sizes, int n_in,
                              void* d_out, int out_size, void* d_ws, size_t ws_size,
                              hipStream_t stream) {
    const float4* x = (const float4*)d_in[0];
    const float4* y = (const float4*)d_in[1];
    // d_in[2] is `shape` (=144, full extent — slicing is a no-op).
    float* bsum = (float*)d_ws;   // 324 floats of scratch
    float* out  = (float*)d_out;

    spe_partial<<<NBLK, 512, 0, stream>>>(x, y, bsum);
    spe_final<<<1, 512, 0, stream>>>(bsum, out);
}

// Round 2
// 35.569 us; speedup vs baseline: 1.0119x; 1.0119x over previous
//
#include <hip/hip_runtime.h>
#include <math.h>

// Spe loss: per-pixel cosine-angle between x[:, :, h, w] and y[:, :, h, w]
// reduced over B*C=1024, then mean of acos over 144*144 pixels.
// Round 2: bc-split x8 across blocks to fix occupancy (was 20%, grid too small).

constexpr int PLANE = 144 * 144;     // 20736 pixels per (b,c) plane (contiguous)
constexpr int QUADS = PLANE / 4;     // 5184 float4 quads per plane
constexpr int BC    = 16 * 64;       // 1024 reduction depth
constexpr int QPB   = 16;            // pixel-quads per block (64 pixels)
constexpr int NG    = 32;            // bc groups per block
constexpr int SPLIT = 8;             // bc splits across blockIdx.y
constexpr int BCS   = BC / SPLIT;    // 128 bc per split
constexpr int ITERS = BCS / NG;      // 4 load-pair iterations per thread
constexpr int NBLK  = QUADS / QPB;   // 324 blocks in x
constexpr int NPIX  = PLANE;
constexpr int B2    = 81;            // stage-2 blocks (81 * 256 = 20736 pixels)

__device__ inline void xor_fold(float4& v, int mask) {
    v.x += __shfl_xor(v.x, mask);
    v.y += __shfl_xor(v.y, mask);
    v.z += __shfl_xor(v.z, mask);
    v.w += __shfl_xor(v.w, mask);
}

__global__ __launch_bounds__(512) void spe_partial(const float4* __restrict__ x,
                                                   const float4* __restrict__ y,
                                                   float4* __restrict__ fzp,
                                                   float4* __restrict__ xxp,
                                                   float4* __restrict__ yyp)
{
    const int tid = threadIdx.x;
    const int q   = tid & (QPB - 1);   // quad within block: 0..15
    const int g   = tid >> 4;          // bc group: 0..31
    const int qg  = blockIdx.x * QPB + q;
    const int s   = blockIdx.y;        // bc split: 0..7

    float4 fz = make_float4(0.f, 0.f, 0.f, 0.f);
    float4 xx = make_float4(0.f, 0.f, 0.f, 0.f);
    float4 yy = make_float4(0.f, 0.f, 0.f, 0.f);

    size_t idx = ((size_t)s * BCS + g) * QUADS + (size_t)qg;
    const size_t step = (size_t)NG * QUADS;
    #pragma unroll
    for (int i = 0; i < ITERS; ++i) {       // 4 iterations, 8 loads in flight
        float4 a = x[idx];
        float4 b = y[idx];
        fz.x = fmaf(a.x, b.x, fz.x); fz.y = fmaf(a.y, b.y, fz.y);
        fz.z = fmaf(a.z, b.z, fz.z); fz.w = fmaf(a.w, b.w, fz.w);
        xx.x = fmaf(a.x, a.x, xx.x); xx.y = fmaf(a.y, a.y, xx.y);
        xx.z = fmaf(a.z, a.z, xx.z); xx.w = fmaf(a.w, a.w, xx.w);
        yy.x = fmaf(b.x, b.x, yy.x); yy.y = fmaf(b.y, b.y, yy.y);
        yy.z = fmaf(b.z, b.z, yy.z); yy.w = fmaf(b.w, b.w, yy.w);
        idx += step;
    }

    // Fold the wave's 4 bc-groups (tid bits 4,5) in-register.
    xor_fold(fz, 16); xor_fold(fz, 32);
    xor_fold(xx, 16); xor_fold(xx, 32);
    xor_fold(yy, 16); xor_fold(yy, 32);

    // Cross-wave fold via LDS: 8 waves x 16 quads.
    __shared__ float4 lfz[8][QPB], lxx[8][QPB], lyy[8][QPB];
    const int wave = tid >> 6;
    if ((tid & 63) < QPB) {
        lfz[wave][q] = fz; lxx[wave][q] = xx; lyy[wave][q] = yy;
    }
    __syncthreads();

    if (tid < QPB) {
        float4 F = lfz[0][tid], X = lxx[0][tid], Y = lyy[0][tid];
        #pragma unroll
        for (int wv = 1; wv < 8; ++wv) {
            F.x += lfz[wv][tid].x; F.y += lfz[wv][tid].y;
            F.z += lfz[wv][tid].z; F.w += lfz[wv][tid].w;
            X.x += lxx[wv][tid].x; X.y += lxx[wv][tid].y;
            X.z += lxx[wv][tid].z; X.w += lxx[wv][tid].w;
            Y.x += lyy[wv][tid].x; Y.y += lyy[wv][tid].y;
            Y.z += lyy[wv][tid].z; Y.w += lyy[wv][tid].w;
        }
        const size_t o = (size_t)s * QUADS + (size_t)(blockIdx.x * QPB + tid);
        fzp[o] = F; xxp[o] = X; yyp[o] = Y;
    }
}

__global__ __launch_bounds__(256) void spe_stage2(const float* __restrict__ fzp,
                                                  const float* __restrict__ xxp,
                                                  const float* __restrict__ yyp,
                                                  float* __restrict__ bsum)
{
    const int t = threadIdx.x;
    const int p = blockIdx.x * 256 + t;    // pixel index, 0..20735

    float F = 0.f, X = 0.f, Y = 0.f;
    #pragma unroll
    for (int s = 0; s < SPLIT; ++s) {
        F += fzp[s * NPIX + p];
        X += xxp[s * NPIX + p];
        Y += yyp[s * NPIX + p];
    }
    float r = F / (sqrtf(X) * sqrtf(Y));
    r = fminf(1.f, fmaxf(-1.f, r));
    float v = acosf(r);

    // Block reduce 256 values: 4 waves.
    __shared__ float l[4];
    #pragma unroll
    for (int off = 32; off >= 1; off >>= 1) v += __shfl_down(v, off);
    if ((t & 63) == 0) l[t >> 6] = v;
    __syncthreads();
    if (t == 0) bsum[blockIdx.x] = l[0] + l[1] + l[2] + l[3];
}

__global__ __launch_bounds__(128) void spe_final(const float* __restrict__ bsum,
                                                 float* __restrict__ out)
{
    __shared__ float l[2];
    const int t = threadIdx.x;
    float s = (t < B2) ? bsum[t] : 0.f;
    #pragma unroll
    for (int off = 32; off >= 1; off >>= 1) s += __shfl_down(s, off);
    if ((t & 63) == 0) l[t >> 6] = s;
    __syncthreads();
    if (t == 0) out[0] = (l[0] + l[1]) * (1.0f / (float)PLANE);
}

extern "C" void kernel_launch(void* const* d_in, const int* in_sizes, int n_in,
                              void* d_out, int out_size, void* d_ws, size_t ws_size,
                              hipStream_t stream) {
    const float4* x = (const float4*)d_in[0];
    const float4* y = (const float4*)d_in[1];
    // d_in[2] is `shape` (=144, full extent — slicing is a no-op).

    float* ws  = (float*)d_ws;
    float* fzp = ws;                       // SPLIT * PLANE floats
    float* xxp = ws + (size_t)SPLIT * NPIX;
    float* yyp = ws + (size_t)2 * SPLIT * NPIX;
    float* bsum = ws + (size_t)3 * SPLIT * NPIX;   // 81 floats
    float* out  = (float*)d_out;

    dim3 grid(NBLK, SPLIT);
    spe_partial<<<grid, 512, 0, stream>>>(x, y, (float4*)fzp, (float4*)xxp, (float4*)yyp);
    spe_stage2<<<B2, 256, 0, stream>>>(fzp, xxp, yyp, bsum);
    spe_final<<<1, 128, 0, stream>>>(bsum, out);
}

// Round 3
// 35.063 us; speedup vs baseline: 1.0265x; 1.0144x over previous
//
#include <hip/hip_runtime.h>
#include <math.h>

// Spe loss: per-pixel cosine-angle between x[:, :, h, w] and y[:, :, h, w]
// reduced over B*C=1024, then mean of acos over 144*144 pixels.
// Round 3: explicit ILP (8 float4 loads in flight; VGPR was 20 = serialized
// latency chain) + wave-contiguous 1KB loads (one plane-strip per wave).

constexpr int PLANE  = 144 * 144;     // 20736 pixels per (b,c) plane (contiguous)
constexpr int QUADS  = PLANE / 4;     // 5184 float4 quads per plane
constexpr int BC     = 16 * 64;       // 1024 reduction depth
constexpr int SPLIT  = 8;             // bc splits across blockIdx.y (ws = 2 MB)
constexpr int BCS    = BC / SPLIT;    // 128 planes per split
constexpr int WAVES  = 8;             // waves per block
constexpr int PPW    = BCS / WAVES;   // 16 planes per wave
constexpr int CHUNK  = 4;             // planes loaded per ILP chunk
constexpr int NCHUNK = PPW / CHUNK;   // 4 chunks
constexpr int NBLK   = QUADS / 64;    // 81 blocks in x (64 quads per block)
constexpr int B2     = 81;            // stage-2 blocks (81 * 256 = 20736 pixels)

__global__ __launch_bounds__(512) void spe_partial(const float4* __restrict__ x,
                                                   const float4* __restrict__ y,
                                                   float4* __restrict__ fzp,
                                                   float4* __restrict__ xxp,
                                                   float4* __restrict__ yyp)
{
    const int tid  = threadIdx.x;
    const int lane = tid & 63;
    const int w    = tid >> 6;                 // wave: 0..7
    const int s    = blockIdx.y;               // bc split: 0..7
    const int qq   = blockIdx.x * 64 + lane;   // quad within plane: wave reads 1KB contiguous

    float4 fz = make_float4(0.f, 0.f, 0.f, 0.f);
    float4 xx = make_float4(0.f, 0.f, 0.f, 0.f);
    float4 yy = make_float4(0.f, 0.f, 0.f, 0.f);

    // planes for this wave: p = s*BCS + i*WAVES + w, i = 0..PPW-1
    size_t idx = ((size_t)s * BCS + w) * QUADS + (size_t)qq;
    const size_t pstep = (size_t)WAVES * QUADS;    // advance 8 planes

    #pragma unroll 1
    for (int c = 0; c < NCHUNK; ++c) {
        float4 a[CHUNK], b[CHUNK];
        size_t i0 = idx;
        #pragma unroll
        for (int u = 0; u < CHUNK; ++u) {      // 8 loads issued back-to-back
            a[u] = x[i0];
            b[u] = y[i0];
            i0 += pstep;
        }
        #pragma unroll
        for (int u = 0; u < CHUNK; ++u) {
            fz.x = fmaf(a[u].x, b[u].x, fz.x); fz.y = fmaf(a[u].y, b[u].y, fz.y);
            fz.z = fmaf(a[u].z, b[u].z, fz.z); fz.w = fmaf(a[u].w, b[u].w, fz.w);
            xx.x = fmaf(a[u].x, a[u].x, xx.x); xx.y = fmaf(a[u].y, a[u].y, xx.y);
            xx.z = fmaf(a[u].z, a[u].z, xx.z); xx.w = fmaf(a[u].w, a[u].w, xx.w);
            yy.x = fmaf(b[u].x, b[u].x, yy.x); yy.y = fmaf(b[u].y, b[u].y, yy.y);
            yy.z = fmaf(b[u].z, b[u].z, yy.z); yy.w = fmaf(b[u].w, b[u].w, yy.w);
        }
        idx += pstep * CHUNK;
    }

    // Cross-wave fold: 8 waves each hold a partial for the same 64 quads.
    __shared__ float4 lf[WAVES][64], lx[WAVES][64], ly[WAVES][64];   // 24 KB
    lf[w][lane] = fz; lx[w][lane] = xx; ly[w][lane] = yy;
    __syncthreads();

    if (tid < 64) {
        float4 F = lf[0][tid], X = lx[0][tid], Y = ly[0][tid];
        #pragma unroll
        for (int wv = 1; wv < WAVES; ++wv) {
            F.x += lf[wv][tid].x; F.y += lf[wv][tid].y;
            F.z += lf[wv][tid].z; F.w += lf[wv][tid].w;
            X.x += lx[wv][tid].x; X.y += lx[wv][tid].y;
            X.z += lx[wv][tid].z; X.w += lx[wv][tid].w;
            Y.x += ly[wv][tid].x; Y.y += ly[wv][tid].y;
            Y.z += ly[wv][tid].z; Y.w += ly[wv][tid].w;
        }
        const size_t o = (size_t)s * QUADS + (size_t)(blockIdx.x * 64 + tid);
        fzp[o] = F; xxp[o] = X; yyp[o] = Y;
    }
}

__global__ __launch_bounds__(256) void spe_stage2(const float* __restrict__ fzp,
                                                  const float* __restrict__ xxp,
                                                  const float* __restrict__ yyp,
                                                  float* __restrict__ bsum)
{
    const int t = threadIdx.x;
    const int p = blockIdx.x * 256 + t;    // pixel index, 0..20735

    float F = 0.f, X = 0.f, Y = 0.f;
    #pragma unroll
    for (int s = 0; s < SPLIT; ++s) {
        F += fzp[s * PLANE + p];
        X += xxp[s * PLANE + p];
        Y += yyp[s * PLANE + p];
    }
    float r = F / (sqrtf(X) * sqrtf(Y));
    r = fminf(1.f, fmaxf(-1.f, r));
    float v = acosf(r);

    __shared__ float l[4];
    #pragma unroll
    for (int off = 32; off >= 1; off >>= 1) v += __shfl_down(v, off);
    if ((t & 63) == 0) l[t >> 6] = v;
    __syncthreads();
    if (t == 0) bsum[blockIdx.x] = l[0] + l[1] + l[2] + l[3];
}

__global__ __launch_bounds__(128) void spe_final(const float* __restrict__ bsum,
                                                 float* __restrict__ out)
{
    __shared__ float l[2];
    const int t = threadIdx.x;
    float s = (t < B2) ? bsum[t] : 0.f;
    #pragma unroll
    for (int off = 32; off >= 1; off >>= 1) s += __shfl_down(s, off);
    if ((t & 63) == 0) l[t >> 6] = s;
    __syncthreads();
    if (t == 0) out[0] = (l[0] + l[1]) * (1.0f / (float)PLANE);
}

extern "C" void kernel_launch(void* const* d_in, const int* in_sizes, int n_in,
                              void* d_out, int out_size, void* d_ws, size_t ws_size,
                              hipStream_t stream) {
    const float4* x = (const float4*)d_in[0];
    const float4* y = (const float4*)d_in[1];
    // d_in[2] is `shape` (=144, full extent — slicing is a no-op).

    float* ws   = (float*)d_ws;
    float* fzp  = ws;                                  // SPLIT * PLANE floats
    float* xxp  = ws + (size_t)SPLIT * PLANE;
    float* yyp  = ws + (size_t)2 * SPLIT * PLANE;
    float* bsum = ws + (size_t)3 * SPLIT * PLANE;      // 81 floats
    float* out  = (float*)d_out;

    dim3 grid(NBLK, SPLIT);
    spe_partial<<<grid, 512, 0, stream>>>(x, y, (float4*)fzp, (float4*)xxp, (float4*)yyp);
    spe_stage2<<<B2, 256, 0, stream>>>(fzp, xxp, yyp, bsum);
    spe_final<<<1, 128, 0, stream>>>(bsum, out);
}